// Round 6
// baseline (480.186 us; speedup 1.0000x reference)
//
#include <hip/hip_runtime.h>
#include <hip/hip_bf16.h>
#include <stdint.h>

#define B_   128
#define N_   196
#define E_   2048
#define D_   512
#define A_   512
#define MTOT (B_ * N_)   // 25088 = 392*64 exactly

typedef short  short8  __attribute__((ext_vector_type(8)));
typedef float  floatx4 __attribute__((ext_vector_type(4)));

__device__ __forceinline__ unsigned short f2bf(float f) {
    union { float f; uint32_t u; } v; v.f = f;
    uint32_t r = v.u + 0x7FFFu + ((v.u >> 16) & 1u);   // RNE
    return (unsigned short)(r >> 16);
}

// pack two fp32 -> two bf16 (round-half-up) in one dword: lo=bf16(a), hi=bf16(b)
__device__ __forceinline__ uint32_t pkbf(float a, float b) {
    uint32_t ua = __float_as_uint(a) + 0x8000u;
    uint32_t ub = __float_as_uint(b) + 0x8000u;
    return __builtin_amdgcn_perm(ub, ua, 0x07060302u);
}

// ---------------------------------------------------------------------------
// Kernel A2: We [2048][512] fp32 -> WeT [512][2048] bf16 (k-contiguous rows)
// ---------------------------------------------------------------------------
__global__ void transcvt_k(const float* __restrict__ We, unsigned short* __restrict__ WeT) {
    __shared__ float tile[32][33];
    const int e0 = blockIdx.x * 32, a0 = blockIdx.y * 32;
    const int t = threadIdx.x, tc = t & 31, tr = t >> 5;   // tr 0..7
#pragma unroll
    for (int i = 0; i < 4; ++i) {
        int r = tr + i * 8;
        tile[r][tc] = We[(size_t)(e0 + r) * A_ + a0 + tc];
    }
    __syncthreads();
#pragma unroll
    for (int i = 0; i < 4; ++i) {
        int r = tr + i * 8;
        WeT[(size_t)(a0 + r) * E_ + e0 + tc] = f2bf(tile[tc][r]);
    }
}

// ---------------------------------------------------------------------------
// Kernel A: att2p[b][a] = dh[b,:]@Wd[:,a] + bd[a] + be[a]   (fp32, tiny)
// ---------------------------------------------------------------------------
__launch_bounds__(512)
__global__ void att2_k(const float* __restrict__ dh, const float* __restrict__ Wd,
                       const float* __restrict__ bd, const float* __restrict__ be,
                       float* __restrict__ att2p) {
    const int b = blockIdx.x, t = threadIdx.x;
    __shared__ float sdh[D_];
    sdh[t] = dh[b * D_ + t];
    __syncthreads();
    float acc = 0.f;
#pragma unroll 8
    for (int d = 0; d < D_; ++d) acc += sdh[d] * Wd[(size_t)d * A_ + t];
    att2p[(size_t)b * A_ + t] = acc + bd[t] + be[t];
}

// ---------------------------------------------------------------------------
// Kernel B: fused bf16 MFMA GEMM (enc @ We) + tanh + dot(Wf) score epilogue.
// Block = 64 rows x ALL 512 cols (enc crosses HBM once). 8 waves, wave=64x64.
// LDS-minimal K-loop (36 KB/iter vs 136 in R5):
//   - B: global->register direct from L2-resident WeT (never in LDS)
//   - A: bf16 in LDS, double-buffered 2x4KB, staged via reg round-trip
//     (float4 prefetched 2 iters ahead -> v_perm pack -> ds_write_b64),
//     one barrier per iter. Bank-conflict-free by construction.
// ---------------------------------------------------------------------------
__launch_bounds__(512, 4)
__global__ void score_gemm(const float* __restrict__ enc,
                           const unsigned short* __restrict__ WeT,
                           const float* __restrict__ att2p,
                           const float* __restrict__ Wf,
                           float* __restrict__ scoresP) {
    __shared__ __align__(16) unsigned short sA[2][64 * 32];   // 2 x 4 KB bf16
    __shared__ float sPart[8][64];

    const int t   = threadIdx.x;
    const int w   = t >> 6;               // 0..7
    const int l   = t & 63;
    const int l15 = l & 15;
    const int q4  = l >> 4;
    const int row0 = blockIdx.x * 64;     // grid = 392

    floatx4 acc[4][4] = {};

    // ---- A global: thread t loads row r = t>>3, k-chunk (t&7)*4 (float4)
    const int ar = t >> 3, ac = t & 7;
    const float* aG = enc + (size_t)(row0 + ar) * E_ + ac * 4;
    // A LDS write: bf16 element offset r*32 + ac*4 (8 bytes per thread)
    unsigned short* aW[2] = { &sA[0][ar * 32 + ac * 4], &sA[1][ar * 32 + ac * 4] };
    // A frag read: row mi*16+l15, k = q4*8..+7 -> element offset +mi*512
    const int aRoff = l15 * 32 + q4 * 8;

    // ---- B global pointers: wave w owns cols w*64 + ni*16 + l15
    const int cbase = w * 64;
    const unsigned short* pb[4];
#pragma unroll
    for (int ni = 0; ni < 4; ++ni)
        pb[ni] = WeT + (size_t)(cbase + ni * 16 + l15) * E_ + q4 * 8;

    // ---- prologue: A(0) staged, A(1) in regs, B(0) in regs
    float4 Araw = *(const float4*)(aG);                 // chunk 0
    short8 Bcur[4];
#pragma unroll
    for (int ni = 0; ni < 4; ++ni) Bcur[ni] = *(const short8*)(pb[ni]);
    {
        uint2 hv; hv.x = pkbf(Araw.x, Araw.y); hv.y = pkbf(Araw.z, Araw.w);
        *(uint2*)aW[0] = hv;
    }
    Araw = *(const float4*)(aG + 32);                   // chunk 1
    __syncthreads();

    for (int kk = 0; kk < 64; ++kk) {
        const unsigned short* aBuf = sA[kk & 1];
        // 1) A fragments for this step
        short8 af[4];
#pragma unroll
        for (int mi = 0; mi < 4; ++mi)
            af[mi] = *(const short8*)(aBuf + aRoff + mi * 512);
        // 2) stage A(kk+1) into the other buffer
        if (kk < 63) {
            uint2 hv; hv.x = pkbf(Araw.x, Araw.y); hv.y = pkbf(Araw.z, Araw.w);
            *(uint2*)aW[(kk + 1) & 1] = hv;
        }
        // 3) prefetch A(kk+2) raw
        if (kk < 62) Araw = *(const float4*)(aG + (kk + 2) * 32);
        // 4) prefetch B(kk+1)
        short8 Bn[4];
        if (kk < 63) {
#pragma unroll
            for (int ni = 0; ni < 4; ++ni)
                Bn[ni] = *(const short8*)(pb[ni] + (kk + 1) * 32);
        }
        // 5) MFMAs
#pragma unroll
        for (int mi = 0; mi < 4; ++mi) {
            acc[mi][0] = __builtin_amdgcn_mfma_f32_16x16x32_bf16(af[mi], Bcur[0], acc[mi][0], 0, 0, 0);
            acc[mi][1] = __builtin_amdgcn_mfma_f32_16x16x32_bf16(af[mi], Bcur[1], acc[mi][1], 0, 0, 0);
            acc[mi][2] = __builtin_amdgcn_mfma_f32_16x16x32_bf16(af[mi], Bcur[2], acc[mi][2], 0, 0, 0);
            acc[mi][3] = __builtin_amdgcn_mfma_f32_16x16x32_bf16(af[mi], Bcur[3], acc[mi][3], 0, 0, 0);
        }
#pragma unroll
        for (int ni = 0; ni < 4; ++ni) Bcur[ni] = Bn[ni];
        __syncthreads();
    }

    // Epilogue: s[m] = sum over ALL 512 cols of tanh(acc + att2p)*Wf
    float wfv[4];
#pragma unroll
    for (int ni = 0; ni < 4; ++ni) wfv[ni] = Wf[cbase + ni * 16 + l15];

#pragma unroll
    for (int mi = 0; mi < 4; ++mi) {
#pragma unroll
        for (int r = 0; r < 4; ++r) {
            const int m    = mi * 16 + q4 * 4 + r;     // D layout: row=(l>>4)*4+reg
            const int grow = row0 + m;
            const int bb   = grow / N_;
            const float* a2 = att2p + (size_t)bb * A_ + cbase;
            float s = 0.f;
#pragma unroll
            for (int ni = 0; ni < 4; ++ni) {
                float v  = acc[mi][ni][r] + a2[ni * 16 + l15];
                float e  = __expf(2.f * v);
                float th = 1.f - 2.f / (e + 1.f);      // tanh(v)
                s += th * wfv[ni];
            }
            s += __shfl_xor(s, 1);
            s += __shfl_xor(s, 2);
            s += __shfl_xor(s, 4);
            s += __shfl_xor(s, 8);
            if (l15 == 0) sPart[w][m] = s;
        }
    }
    __syncthreads();
    if (t < 64) {
        float v = 0.f;
#pragma unroll
        for (int ww = 0; ww < 8; ++ww) v += sPart[ww][t];
        scoresP[row0 + t] = v;
    }
}

// ---------------------------------------------------------------------------
// Kernel C0: softmax over N=196 per batch (bf bias dropped — softmax-invariant)
// ---------------------------------------------------------------------------
__global__ void softmax_k(const float* __restrict__ sp, float* __restrict__ alpha) {
    const int b = blockIdx.x, t = threadIdx.x;
    const int w = t >> 6, l = t & 63;
    __shared__ float red[8];
    float v = -3.0e38f;
    if (t < N_) v = sp[b * N_ + t];
    float m = v;
#pragma unroll
    for (int off = 32; off >= 1; off >>= 1) m = fmaxf(m, __shfl_xor(m, off));
    if (l == 0) red[w] = m;
    __syncthreads();
    m = fmaxf(fmaxf(red[0], red[1]), fmaxf(red[2], red[3]));
    float e = 0.f;
    if (t < N_) e = __expf(v - m);
    float s = e;
#pragma unroll
    for (int off = 32; off >= 1; off >>= 1) s += __shfl_xor(s, off);
    if (l == 0) red[4 + w] = s;
    __syncthreads();
    s = red[4] + red[5] + red[6] + red[7];
    if (t < N_) alpha[b * N_ + t] = e / s;
}

// ---------------------------------------------------------------------------
// Kernel C1: context[b, :] = sum_n alpha[b,n] * enc[b,n,:]   (fp32 stream)
// ---------------------------------------------------------------------------
__launch_bounds__(256)
__global__ void context_k(const float* __restrict__ enc, const float* __restrict__ alpha,
                          float* __restrict__ ctx) {
    const int chunk = blockIdx.x, b = blockIdx.y;
    const int t = threadIdx.x, tn = t >> 6, tc = t & 63;
    __shared__ float  sAl[N_];
    __shared__ float4 sRed[256];
    if (t < N_) sAl[t] = alpha[b * N_ + t];
    __syncthreads();
    const float* base = enc + (size_t)b * N_ * E_ + chunk * 256 + tc * 4;
    float4 a = make_float4(0.f, 0.f, 0.f, 0.f);
#pragma unroll 7
    for (int n = tn; n < N_; n += 4) {
        float  al = sAl[n];
        float4 v  = *(const float4*)(base + (size_t)n * E_);
        a.x += al * v.x; a.y += al * v.y; a.z += al * v.z; a.w += al * v.w;
    }
    sRed[t] = a;
    __syncthreads();
    if (t < 64) {
        float4 r0 = sRed[t], r1 = sRed[t + 64], r2 = sRed[t + 128], r3 = sRed[t + 192];
        float4 o = make_float4(r0.x + r1.x + r2.x + r3.x, r0.y + r1.y + r2.y + r3.y,
                               r0.z + r1.z + r2.z + r3.z, r0.w + r1.w + r2.w + r3.w);
        *(float4*)(ctx + (size_t)b * E_ + chunk * 256 + t * 4) = o;
    }
}

// ---------------------------------------------------------------------------
extern "C" void kernel_launch(void* const* d_in, const int* in_sizes, int n_in,
                              void* d_out, int out_size, void* d_ws, size_t ws_size,
                              hipStream_t stream) {
    const float* enc = (const float*)d_in[0];
    const float* dh  = (const float*)d_in[1];
    const float* We  = (const float*)d_in[2];
    const float* be  = (const float*)d_in[3];
    const float* Wd  = (const float*)d_in[4];
    const float* bd  = (const float*)d_in[5];
    const float* Wf  = (const float*)d_in[6];
    // d_in[7] = bf: additive constant on scores, cancels in softmax.

    float* out   = (float*)d_out;
    float* ctx   = out;              // [128, 2048]
    float* alpha = out + B_ * E_;    // [128, 196]

    char* ws = (char*)d_ws;
    unsigned short* WeT  = (unsigned short*)ws;                       // 2 MB
    float* att2p         = (float*)(ws + (2u << 20));                 // 256 KB
    float* scoresP       = (float*)(ws + (2u << 20) + (256u << 10));  // 25088 fp32

    transcvt_k <<<dim3(E_ / 32, A_ / 32), 256, 0, stream>>>(We, WeT);
    att2_k     <<<dim3(B_),              512, 0, stream>>>(dh, Wd, bd, be, att2p);
    score_gemm <<<dim3(MTOT / 64),       512, 0, stream>>>(enc, WeT, att2p, Wf, scoresP);
    softmax_k  <<<dim3(B_),              256, 0, stream>>>(scoresP, alpha);
    context_k  <<<dim3(E_ / 256, B_),    256, 0, stream>>>(enc, alpha, ctx);
}

// Round 7
// 466.193 us; speedup vs baseline: 1.0300x; 1.0300x over previous
//
#include <hip/hip_runtime.h>
#include <hip/hip_bf16.h>
#include <stdint.h>

#define B_   128
#define N_   196
#define E_   2048
#define D_   512
#define A_   512
#define MTOT (B_ * N_)   // 25088 = 392*64 exactly

typedef short  short8  __attribute__((ext_vector_type(8)));
typedef float  floatx4 __attribute__((ext_vector_type(4)));

__device__ __forceinline__ unsigned short f2bf(float f) {
    union { float f; uint32_t u; } v; v.f = f;
    uint32_t r = v.u + 0x7FFFu + ((v.u >> 16) & 1u);   // RNE
    return (unsigned short)(r >> 16);
}

// pack two fp32 -> two bf16 (round-half-up) in one dword: lo=bf16(a), hi=bf16(b)
__device__ __forceinline__ uint32_t pkbf(float a, float b) {
    uint32_t ua = __float_as_uint(a) + 0x8000u;
    uint32_t ub = __float_as_uint(b) + 0x8000u;
    return __builtin_amdgcn_perm(ub, ua, 0x07060302u);
}

// ---------------------------------------------------------------------------
// Kernel A2: We [2048][512] fp32 -> WeT2 bf16 TILED layout:
//   elem(a, e) -> (a>>4)*32768 + (e>>5)*512 + ((e>>3)&3)*128 + (a&15)*8 + (e&7)
// so a 64-lane B-load for one (a-tile, 32-k step) is ONE contiguous 1 KB burst
// (kills the 4 KB-stride L2 channel conflicts of the row-major layout).
// ---------------------------------------------------------------------------
__global__ void transcvt_k(const float* __restrict__ We, unsigned short* __restrict__ WeT2) {
    const int t   = threadIdx.x;
    const int l15 = t & 15;              // a & 15
    const int q4  = (t >> 4) & 3;        // (e>>3)&3
    const int g   = t >> 6;              // kk sub-group
    const int tile = blockIdx.x;         // a>>4   (32)
    const int kk   = blockIdx.y * 4 + g; // e>>5   (64)
    const int a  = tile * 16 + l15;
    const int e0 = kk * 32 + q4 * 8;
    union { unsigned short us[8]; short8 s; } pk;
#pragma unroll
    for (int j = 0; j < 8; ++j)
        pk.us[j] = f2bf(We[(size_t)(e0 + j) * A_ + a]);
    *(short8*)(WeT2 + (size_t)tile * 32768 + kk * 512 + q4 * 128 + l15 * 8) = pk.s;
}

// ---------------------------------------------------------------------------
// Kernel A: att2p[b][a] = dh[b,:]@Wd[:,a] + bd[a] + be[a]   (fp32, tiny)
// ---------------------------------------------------------------------------
__launch_bounds__(512)
__global__ void att2_k(const float* __restrict__ dh, const float* __restrict__ Wd,
                       const float* __restrict__ bd, const float* __restrict__ be,
                       float* __restrict__ att2p) {
    const int b = blockIdx.x, t = threadIdx.x;
    __shared__ float sdh[D_];
    sdh[t] = dh[b * D_ + t];
    __syncthreads();
    float acc = 0.f;
#pragma unroll 8
    for (int d = 0; d < D_; ++d) acc += sdh[d] * Wd[(size_t)d * A_ + t];
    att2p[(size_t)b * A_ + t] = acc + bd[t] + be[t];
}

// ---------------------------------------------------------------------------
// Kernel B: fused bf16 MFMA GEMM (enc @ We) + tanh + dot(Wf) score epilogue.
// m97 recipe: 256 thr (4 waves), tile 64 rows x 256 cols, BK=32, single-buffer
// LDS, 2 barriers/iter, BOTH operands via global_load_lds:
//   A: raw fp32, 16-row tiles in [c16][l15][4e] layout (8 KB), pack at read.
//   B: bf16 from TILED WeT2 -> contiguous 1 KB DMA bursts (16 KB).
// All LDS reads/writes at the bank floor by construction (no swizzle).
// 784 blocks -> ~3 co-resident blocks/CU hide the barrier vmcnt drains.
// ---------------------------------------------------------------------------
__launch_bounds__(256, 3)
__global__ void score_gemm(const float* __restrict__ enc,
                           const unsigned short* __restrict__ WeT2,
                           const float* __restrict__ att2p,
                           const float* __restrict__ Wf,
                           float* __restrict__ scoresP) {
    // A: 4 r-tiles x 2 KB  = 8 KB   (tile rt: [c16 0..7][l15][4 fp32])
    // B: 16 c-tiles x 1 KB = 16 KB  (tile ct: [q4][l15][8 bf16])
    __shared__ __align__(16) char sMem[8192 + 16384];
    __shared__ float sPart[4][64];

    const int t   = threadIdx.x;
    const int w   = t >> 6;               // 0..3
    const int l   = t & 63;
    const int l15 = l & 15;
    const int q4  = l >> 4;
    const int row0 = blockIdx.y * 64;     // grid.y = 392
    const int col0 = blockIdx.x * 256;    // grid.x = 2

    floatx4 acc[4][4] = {};

    // ---- A DMA: wave w stages r-tile rt=w (16 rows x 32 k fp32) in 2 instrs
    const float* aSrc[2];
    int aDst[2];
#pragma unroll
    for (int h = 0; h < 2; ++h) {
        aSrc[h] = enc + (size_t)(row0 + w * 16 + l15) * E_ + (4 * h + q4) * 4;
        aDst[h] = w * 2048 + h * 1024 + l * 16;
    }
    // ---- B DMA: wave w stages c-tiles w*4..w*4+3, 1 contiguous KB each
    const unsigned short* bSrc[4];
    int bDst[4];
#pragma unroll
    for (int j = 0; j < 4; ++j) {
        bSrc[j] = WeT2 + (size_t)((col0 >> 4) + w * 4 + j) * 32768 + l * 8;
        bDst[j] = 8192 + (w * 4 + j) * 1024 + l * 16;
    }

    // ---- frag read offsets
    //  A (fp32): mi-tile base + c16 = 2*q4 (+1) -> two float4, banks at floor
    const int offAlo = (2 * q4) * 256 + l15 * 16;          // + mi*2048
    //  B (bf16): ct = w*4+ni
    const int offB   = 8192 + w * 4096 + q4 * 256 + l15 * 16;  // + ni*1024

    for (int kk = 0; kk < 64; ++kk) {
#pragma unroll
        for (int h = 0; h < 2; ++h)
            __builtin_amdgcn_global_load_lds(
                (const __attribute__((address_space(1))) uint32_t*)(aSrc[h] + kk * 32),
                (__attribute__((address_space(3))) uint32_t*)(sMem + aDst[h]), 16, 0, 0);
#pragma unroll
        for (int j = 0; j < 4; ++j)
            __builtin_amdgcn_global_load_lds(
                (const __attribute__((address_space(1))) uint32_t*)(bSrc[j] + kk * 512),
                (__attribute__((address_space(3))) uint32_t*)(sMem + bDst[j]), 16, 0, 0);
        __syncthreads();

        short8 bfr[4];
        union { uint32_t u[4]; short8 s; } af[4];
#pragma unroll
        for (int ni = 0; ni < 4; ++ni)
            bfr[ni] = *(const short8*)(sMem + offB + ni * 1024);
#pragma unroll
        for (int mi = 0; mi < 4; ++mi) {
            float4 lo = *(const float4*)(sMem + mi * 2048 + offAlo);        // k q4*8..+3
            float4 hi = *(const float4*)(sMem + mi * 2048 + offAlo + 256);  // k q4*8+4..+7
            af[mi].u[0] = pkbf(lo.x, lo.y);
            af[mi].u[1] = pkbf(lo.z, lo.w);
            af[mi].u[2] = pkbf(hi.x, hi.y);
            af[mi].u[3] = pkbf(hi.z, hi.w);
        }
#pragma unroll
        for (int mi = 0; mi < 4; ++mi) {
            acc[mi][0] = __builtin_amdgcn_mfma_f32_16x16x32_bf16(af[mi].s, bfr[0], acc[mi][0], 0, 0, 0);
            acc[mi][1] = __builtin_amdgcn_mfma_f32_16x16x32_bf16(af[mi].s, bfr[1], acc[mi][1], 0, 0, 0);
            acc[mi][2] = __builtin_amdgcn_mfma_f32_16x16x32_bf16(af[mi].s, bfr[2], acc[mi][2], 0, 0, 0);
            acc[mi][3] = __builtin_amdgcn_mfma_f32_16x16x32_bf16(af[mi].s, bfr[3], acc[mi][3], 0, 0, 0);
        }
        __syncthreads();
    }

    // Epilogue: s[m] += sum_n tanh(acc + att2p[b(m),n]) * Wf[n]  (partial, 256 cols)
    const int cbase = col0 + w * 64;
    float wfv[4];
#pragma unroll
    for (int ni = 0; ni < 4; ++ni) wfv[ni] = Wf[cbase + ni * 16 + l15];

#pragma unroll
    for (int mi = 0; mi < 4; ++mi) {
#pragma unroll
        for (int r = 0; r < 4; ++r) {
            const int m    = mi * 16 + q4 * 4 + r;     // D layout: row=(l>>4)*4+reg
            const int grow = row0 + m;
            const int bb   = grow / N_;
            const float* a2 = att2p + (size_t)bb * A_ + cbase;
            float s = 0.f;
#pragma unroll
            for (int ni = 0; ni < 4; ++ni) {
                float v  = acc[mi][ni][r] + a2[ni * 16 + l15];
                float e  = __expf(2.f * v);
                float th = 1.f - 2.f / (e + 1.f);      // tanh(v)
                s += th * wfv[ni];
            }
            s += __shfl_xor(s, 1);
            s += __shfl_xor(s, 2);
            s += __shfl_xor(s, 4);
            s += __shfl_xor(s, 8);
            if (l15 == 0) sPart[w][m] = s;
        }
    }
    __syncthreads();
    if (t < 64) {
        float v = sPart[0][t] + sPart[1][t] + sPart[2][t] + sPart[3][t];
        scoresP[(size_t)blockIdx.x * MTOT + row0 + t] = v;
    }
}

// ---------------------------------------------------------------------------
// Kernel C0: softmax over N=196 per batch (2 col-tile partials; bf dropped)
// ---------------------------------------------------------------------------
__global__ void softmax_k(const float* __restrict__ sp, float* __restrict__ alpha) {
    const int b = blockIdx.x, t = threadIdx.x;
    const int w = t >> 6, l = t & 63;
    __shared__ float red[8];
    float v = -3.0e38f;
    if (t < N_) v = sp[b * N_ + t] + sp[MTOT + b * N_ + t];
    float m = v;
#pragma unroll
    for (int off = 32; off >= 1; off >>= 1) m = fmaxf(m, __shfl_xor(m, off));
    if (l == 0) red[w] = m;
    __syncthreads();
    m = fmaxf(fmaxf(red[0], red[1]), fmaxf(red[2], red[3]));
    float e = 0.f;
    if (t < N_) e = __expf(v - m);
    float s = e;
#pragma unroll
    for (int off = 32; off >= 1; off >>= 1) s += __shfl_xor(s, off);
    if (l == 0) red[4 + w] = s;
    __syncthreads();
    s = red[4] + red[5] + red[6] + red[7];
    if (t < N_) alpha[b * N_ + t] = e / s;
}

// ---------------------------------------------------------------------------
// Kernel C1: context[b, :] = sum_n alpha[b,n] * enc[b,n,:]   (fp32 stream)
// ---------------------------------------------------------------------------
__launch_bounds__(256)
__global__ void context_k(const float* __restrict__ enc, const float* __restrict__ alpha,
                          float* __restrict__ ctx) {
    const int chunk = blockIdx.x, b = blockIdx.y;
    const int t = threadIdx.x, tn = t >> 6, tc = t & 63;
    __shared__ float  sAl[N_];
    __shared__ float4 sRed[256];
    if (t < N_) sAl[t] = alpha[b * N_ + t];
    __syncthreads();
    const float* base = enc + (size_t)b * N_ * E_ + chunk * 256 + tc * 4;
    float4 a = make_float4(0.f, 0.f, 0.f, 0.f);
#pragma unroll 7
    for (int n = tn; n < N_; n += 4) {
        float  al = sAl[n];
        float4 v  = *(const float4*)(base + (size_t)n * E_);
        a.x += al * v.x; a.y += al * v.y; a.z += al * v.z; a.w += al * v.w;
    }
    sRed[t] = a;
    __syncthreads();
    if (t < 64) {
        float4 r0 = sRed[t], r1 = sRed[t + 64], r2 = sRed[t + 128], r3 = sRed[t + 192];
        float4 o = make_float4(r0.x + r1.x + r2.x + r3.x, r0.y + r1.y + r2.y + r3.y,
                               r0.z + r1.z + r2.z + r3.z, r0.w + r1.w + r2.w + r3.w);
        *(float4*)(ctx + (size_t)b * E_ + chunk * 256 + t * 4) = o;
    }
}

// ---------------------------------------------------------------------------
extern "C" void kernel_launch(void* const* d_in, const int* in_sizes, int n_in,
                              void* d_out, int out_size, void* d_ws, size_t ws_size,
                              hipStream_t stream) {
    const float* enc = (const float*)d_in[0];
    const float* dh  = (const float*)d_in[1];
    const float* We  = (const float*)d_in[2];
    const float* be  = (const float*)d_in[3];
    const float* Wd  = (const float*)d_in[4];
    const float* bd  = (const float*)d_in[5];
    const float* Wf  = (const float*)d_in[6];
    // d_in[7] = bf: additive constant on scores, cancels in softmax.

    float* out   = (float*)d_out;
    float* ctx   = out;              // [128, 2048]
    float* alpha = out + B_ * E_;    // [128, 196]

    char* ws = (char*)d_ws;
    unsigned short* WeT2 = (unsigned short*)ws;                       // 2 MB (tiled)
    float* att2p         = (float*)(ws + (2u << 20));                 // 256 KB
    float* scoresP       = (float*)(ws + (2u << 20) + (256u << 10));  // 2 x 25088 fp32

    transcvt_k <<<dim3(32, 16),       256, 0, stream>>>(We, WeT2);
    att2_k     <<<dim3(B_),           512, 0, stream>>>(dh, Wd, bd, be, att2p);
    score_gemm <<<dim3(2, MTOT / 64), 256, 0, stream>>>(enc, WeT2, att2p, Wf, scoresP);
    softmax_k  <<<dim3(B_),           256, 0, stream>>>(scoresP, alpha);
    context_k  <<<dim3(E_ / 256, B_), 256, 0, stream>>>(enc, alpha, ctx);
}